// Round 11
// baseline (137.998 us; speedup 1.0000x reference)
//
#include <hip/hip_runtime.h>
#include <math.h>
#include <limits.h>

// Problem constants (match reference)
#define BD 4
#define ZD 40
#define YD 1024
#define XD 1024
#define BZYX 167772160   // BD*ZD*YD*XD

constexpr int BLOCK = 256;
constexpr unsigned SMALL_LOG = 18;              // 256k slots * 8B = 2 MB
constexpr unsigned SMASK = (1u << SMALL_LOG) - 1;
constexpr size_t BM_BYTES   = (size_t)BZYX / 8;          // 20,971,520
constexpr size_t STAB_BYTES = (size_t)8 << SMALL_LOG;    // 2,097,152

typedef unsigned uvec4 __attribute__((ext_vector_type(4)));

__device__ __forceinline__ unsigned hash_mix(unsigned x) {
    x ^= x >> 16; x *= 0x7feb352dU;
    x ^= x >> 15; x *= 0x846ca68bU;
    x ^= x >> 16;
    return x;
}
__device__ __forceinline__ float smooth_l1(float d) {
    float ad = fabsf(d);
    return (ad < 1.0f) ? 0.5f * d * d : ad - 0.5f;
}
__device__ __forceinline__ float logaddexp0(float l) {
    return (l > 0.0f) ? (l + log1pf(expf(-l))) : log1pf(expf(l));
}

// Flat cell index (r5 layout — fastest measured match):
__device__ __forceinline__ unsigned cell_flat(int b, int z, int y, int x) {
    return ((unsigned)(b * ZD + z) * YD + y) * XD + (unsigned)x;
}
__device__ __forceinline__ bool bm_test(const unsigned* __restrict__ bm, unsigned c) {
    return (bm[c >> 5] >> (c & 31)) & 1u;
}

// R==1 match: 9 u64 window loads (compiler merges to dwordx2 -> 9 L1
// transactions/thread), argmin dL1 with first-k tie-break via masks.
__device__ __forceinline__ bool match27(const unsigned* __restrict__ bm,
                                        int b, int z, int y, int x,
                                        int& sz, int& sy, int& sx) {
    const int xa = max(x - 1, 0);
    const int xc = min(x + 1, XD - 1);
    const int sa = x - xa;          // shift for dx=0
    const int sc = xc - xa;         // shift for dx=+1
    unsigned hm = 0;
#pragma unroll
    for (int dz = -1; dz <= 1; ++dz) {
        const int zz = min(max(z + dz, 0), ZD - 1);
#pragma unroll
        for (int dy = -1; dy <= 1; ++dy) {
            const int yy = min(max(y + dy, 0), YD - 1);
            const unsigned n0 = cell_flat(b, zz, yy, xa);
            const unsigned q = n0 >> 5;
            const int r = n0 & 31;
            unsigned long long w = ((unsigned long long)bm[q + 1] << 32) | bm[q];
            w >>= r;
            const int k0 = (dz + 1) * 9 + (dy + 1) * 3;
            hm |= ((unsigned)(w & 1)) << (k0 + 0);
            hm |= ((unsigned)((w >> sa) & 1)) << (k0 + 1);
            hm |= ((unsigned)((w >> sc) & 1)) << (k0 + 2);
        }
    }
    constexpr unsigned M0 = 1u << 13;
    constexpr unsigned M1 = (1u << 4) | (1u << 10) | (1u << 12) | (1u << 14) | (1u << 16) | (1u << 22);
    constexpr unsigned M2 = (1u << 1) | (1u << 3) | (1u << 5) | (1u << 7) | (1u << 9) | (1u << 11) |
                            (1u << 15) | (1u << 17) | (1u << 19) | (1u << 21) | (1u << 23) | (1u << 25);
    int bk;
    if (hm & M0)      bk = 13;
    else if (hm & M1) bk = __ffs((int)(hm & M1)) - 1;
    else if (hm & M2) bk = __ffs((int)(hm & M2)) - 1;
    else if (hm)      bk = __ffs((int)hm) - 1;
    else return false;
    const int ai = bk / 9, ci = (bk / 3) % 3, di = bk % 3;
    sz = min(max(z + ai - 1, 0), ZD - 1);
    sy = min(max(y + ci - 1, 0), YD - 1);
    sx = (di == 0) ? xa : ((di == 1) ? x : xc);
    return true;
}

__device__ bool matchR(const unsigned* __restrict__ bm, int R,
                       int b, int z, int y, int x, int& sz, int& sy, int& sx) {
    int bestd = INT_MAX; bool m = false;
    for (int dz = -R; dz <= R; ++dz) {
        const int zz = min(max(z + dz, 0), ZD - 1);
        const int adz = abs(dz);
        for (int dy = -R; dy <= R; ++dy) {
            const int yy = min(max(y + dy, 0), YD - 1);
            const int adzy = adz + abs(dy);
            for (int dx = -R; dx <= R; ++dx) {
                const int d = adzy + abs(dx);
                if (d >= bestd) continue;
                const int xx = min(max(x + dx, 0), XD - 1);
                if (bm_test(bm, cell_flat(b, zz, yy, xx))) {
                    bestd = d; m = true; sz = zz; sy = yy; sx = xx;
                }
            }
        }
    }
    return m;
}

// stab encoding (zero-init): 0 = empty; high 32 = cell+1; low 32 = ~row
// accumulated with atomicMax (max(~row) == min(row)).
__device__ __forceinline__ unsigned stab_insert(unsigned long long* stab, unsigned key) {
    const unsigned long long desired = ((unsigned long long)key << 32);
    unsigned s = hash_mix(key) & SMASK;
    while (true) {
        unsigned long long old = atomicCAS(&stab[s], 0ull, desired);
        if (old == 0ull || (unsigned)(old >> 32) == key) return s;
        s = (s + 1) & SMASK;
    }
}
__device__ __forceinline__ void stab_minrow(unsigned long long* stab, unsigned key, unsigned row) {
    unsigned s = hash_mix(key) & SMASK;
    while (true) {
        const unsigned long long e = stab[s];      // key immutable during scan
        if (e == 0ull) return;                     // cell not selected
        if ((unsigned)(e >> 32) == key) {
            atomicMax((unsigned*)&stab[s], ~row);  // low half
            return;
        }
        s = (s + 1) & SMASK;
    }
}

// ---- kernel 1: clear bm + guard + stab + counter (nt streaming) ----
__global__ void k_clear(uvec4* __restrict__ v, int n4) {
    const uvec4 z = (uvec4)(0u);
    const int stride = gridDim.x * blockDim.x;
    for (int k = blockIdx.x * blockDim.x + threadIdx.x; k < n4; k += stride)
        __builtin_nontemporal_store(z, &v[k]);
}

// ---- kernel 2: bitmap build + compact cell ids ----
__global__ void k_build(const int4* __restrict__ li, int Nl,
                        unsigned* __restrict__ bm, unsigned* __restrict__ cells) {
    const int j = blockIdx.x * blockDim.x + threadIdx.x;
    if (j >= Nl) return;
    int4 v = li[j];  // [b,z,y,x]
    const unsigned c = cell_flat(v.x, v.y, v.z, v.w);
    cells[j] = c;
    atomicOr(&bm[c >> 5], 1u << (c & 31));
}

// ---- kernel 3: radar match + occ/cnt/off sums + stab insert ----
__global__ void __launch_bounds__(BLOCK)
k_match(const float4* __restrict__ pf, const float* __restrict__ occ,
        const int4* __restrict__ ri, const unsigned* __restrict__ bm,
        unsigned long long* __restrict__ stab, const int* __restrict__ Rptr,
        int Nr, int* __restrict__ mcell, double* __restrict__ partials) {
    const int R = *Rptr;
    double occ_s = 0.0, cnt_s = 0.0, off_s = 0.0;
    const int stride = gridDim.x * blockDim.x;
    for (int i = blockIdx.x * BLOCK + threadIdx.x; i < Nr; i += stride) {
        int4 rib = ri[i];
        const int b = rib.x, z = rib.y, y = rib.z, x = rib.w;
        int sz = 0, sy = 0, sx = 0;
        const bool matched = (R == 1) ? match27(bm, b, z, y, x, sz, sy, sx)
                                      : matchR(bm, R, b, z, y, x, sz, sy, sx);
        float m = 0.f; int ms = -1;
        if (matched) {
            m = 1.f; cnt_s += 1.0;
            const float4 pp = pf[i];
            off_s += (double)(smooth_l1(pp.x - (float)(sx - x)) +
                              smooth_l1(pp.y - (float)(sy - y)) +
                              smooth_l1(pp.z - (float)(sz - z)));
            const unsigned c = cell_flat(b, sz, sy, sx);
            ms = (int)stab_insert(stab, c + 1);    // store SLOT for direct feat access
        }
        mcell[i] = ms;
        const float lg = occ[i];
        occ_s += (double)(logaddexp0(lg) - lg * m);
    }
    __shared__ double sh[3][BLOCK];
    const int tid = threadIdx.x;
    sh[0][tid] = occ_s; sh[1][tid] = cnt_s; sh[2][tid] = off_s;
    __syncthreads();
    for (int s = BLOCK / 2; s > 0; s >>= 1) {
        if (tid < s) {
            sh[0][tid] += sh[0][tid + s];
            sh[1][tid] += sh[1][tid + s];
            sh[2][tid] += sh[2][tid + s];
        }
        __syncthreads();
    }
    if (tid == 0) {
        partials[blockIdx.x * 4 + 0] = sh[0][0];
        partials[blockIdx.x * 4 + 1] = sh[1][0];
        partials[blockIdx.x * 4 + 2] = sh[2][0];
        partials[blockIdx.x * 4 + 3] = 0.0;
    }
}

// ---- kernel 4: lidar scan (min original row per selected cell) ----
__global__ void k_scan(const unsigned* __restrict__ cells, int Nl,
                       unsigned long long* __restrict__ stab) {
    const int j = blockIdx.x * blockDim.x + threadIdx.x;
    if (j >= Nl) return;
    stab_minrow(stab, cells[j] + 1, (unsigned)j);
}

// ---- kernel 5: feature loss (direct slot read) + last-block finalize ----
__global__ void __launch_bounds__(BLOCK)
k_feat(const float* __restrict__ pfw, const int* __restrict__ mcell,
       const unsigned long long* __restrict__ stab, const float* __restrict__ lf,
       int Nr, double* __restrict__ fpart, const double* __restrict__ partials,
       unsigned* __restrict__ counter, int mblk, float* __restrict__ out) {
    double fs = 0.0;
    const int stride = gridDim.x * blockDim.x;
    for (int i = blockIdx.x * BLOCK + threadIdx.x; i < Nr; i += stride) {
        const int ms = mcell[i];
        if (ms >= 0) {
            const unsigned row = ~((unsigned)stab[ms]);   // low half = ~minrow
            fs += (double)fabsf(pfw[(size_t)i * 4 + 3] - lf[(size_t)row * 4 + 3]);
        }
    }
    __shared__ double sh[4][BLOCK];
    __shared__ bool isLast;
    const int tid = threadIdx.x;
    sh[0][tid] = fs;
    __syncthreads();
    for (int s = BLOCK / 2; s > 0; s >>= 1) {
        if (tid < s) sh[0][tid] += sh[0][tid + s];
        __syncthreads();
    }
    if (tid == 0) {
        fpart[blockIdx.x] = sh[0][0];
        __threadfence();
        const unsigned done = atomicAdd(counter, 1u);
        isLast = (done == gridDim.x - 1);
    }
    __syncthreads();
    if (!isLast) return;

    double a0 = 0, a1 = 0, a2 = 0, a3 = 0;
    for (int k = tid; k < mblk; k += BLOCK) {
        a0 += partials[k * 4 + 0];
        a1 += partials[k * 4 + 1];
        a2 += partials[k * 4 + 2];
    }
    for (int k = tid; k < (int)gridDim.x; k += BLOCK) a3 += fpart[k];
    __syncthreads();
    sh[0][tid] = a0; sh[1][tid] = a1; sh[2][tid] = a2; sh[3][tid] = a3;
    __syncthreads();
    for (int s = BLOCK / 2; s > 0; s >>= 1) {
        if (tid < s) {
            sh[0][tid] += sh[0][tid + s];
            sh[1][tid] += sh[1][tid + s];
            sh[2][tid] += sh[2][tid + s];
            sh[3][tid] += sh[3][tid + s];
        }
        __syncthreads();
    }
    if (tid == 0) {
        const double occ_loss = sh[0][0] / (double)Nr;
        const double cnt = sh[1][0];
        const double off_loss = sh[2][0] / fmax(cnt * 3.0, 1.0);
        const double feat_loss = sh[3][0] / fmax(cnt, 1.0);
        out[0] = (float)(0.2 * occ_loss + 1.0 * off_loss + 1.0 * feat_loss);
    }
}

extern "C" void kernel_launch(void* const* d_in, const int* in_sizes, int n_in,
                              void* d_out, int out_size, void* d_ws, size_t ws_size,
                              hipStream_t stream) {
    const float4* pf = (const float4*)d_in[0];   // (Nr,4)
    const float*  oc = (const float*)d_in[1];    // (Nr,1,1)
    const int4*   ri = (const int4*)d_in[2];     // (Nr,4)
    const float*  lf = (const float*)d_in[3];    // (Nl,4)
    const int4*   li = (const int4*)d_in[4];     // (Nl,4)
    const int*    Rp = (const int*)d_in[5];      // scalar (device)

    const int Nr = in_sizes[0] / 4;
    const int Nl = in_sizes[3] / 4;
    const int nblkL = (Nl + BLOCK - 1) / BLOCK;          // 4096
    int nblk = (Nr + BLOCK - 1) / BLOCK;                 // 1024
    if (nblk > 2048) nblk = 2048;                        // grid-stride beyond

    // Workspace: [bm | 256B zero guard | stab | counter] = one contiguous
    // zero region (guard keeps match27's u64 window overread reading zeros).
    size_t off = 0;
    auto alloc = [&](size_t n) { size_t o = off; off += (n + 255) & ~(size_t)255; return o; };
    char* ws = (char*)d_ws;
    unsigned*           bm      = (unsigned*)(ws + alloc(BM_BYTES + 256));
    unsigned long long* stab    = (unsigned long long*)(ws + alloc(STAB_BYTES));
    unsigned*           counter = (unsigned*)(ws + alloc(256));
    const size_t zeroEnd = off;
    unsigned*           cells = (unsigned*)(ws + alloc((size_t)Nl * 4));
    int*                mcell = (int*)(ws + alloc((size_t)Nr * 4));
    double*             parts = (double*)(ws + alloc((size_t)nblk * 4 * sizeof(double)));
    double*             fpart = (double*)(ws + alloc((size_t)nblk * sizeof(double)));

    k_clear<<<4096, BLOCK, 0, stream>>>((uvec4*)ws, (int)(zeroEnd / 16));
    k_build<<<nblkL, BLOCK, 0, stream>>>(li, Nl, bm, cells);
    k_match<<<nblk, BLOCK, 0, stream>>>(pf, oc, ri, bm, stab, Rp, Nr, mcell, parts);
    k_scan<<<nblkL, BLOCK, 0, stream>>>(cells, Nl, stab);
    k_feat<<<nblk, BLOCK, 0, stream>>>((const float*)pf, mcell, stab, lf, Nr, fpart,
                                       parts, counter, nblk, (float*)d_out);
}

// Round 12
// 117.078 us; speedup vs baseline: 1.1787x; 1.1787x over previous
//
#include <hip/hip_runtime.h>
#include <math.h>
#include <limits.h>

// Problem constants (match reference)
#define BD 4
#define ZD 40
#define YD 1024
#define XD 1024
#define BZYX (167772160)   // BD*ZD*YD*XD

constexpr int BLOCK = 256;
constexpr unsigned SMALL_LOG = 19;                  // 512k slots * 8B = 4 MB
constexpr unsigned long long EMPTY64 = ~0ull;

// Native clang vector type: __builtin_nontemporal_store requires a real
// vector (HIP's uint4 is a struct and is rejected).
typedef unsigned uvec4 __attribute__((ext_vector_type(4)));

__device__ __forceinline__ unsigned hash_mix(unsigned x) {
    x ^= x >> 16; x *= 0x7feb352dU;
    x ^= x >> 15; x *= 0x846ca68bU;
    x ^= x >> 16;
    return x;
}

__device__ __forceinline__ float smooth_l1(float d) {
    float ad = fabsf(d);
    return (ad < 1.0f) ? 0.5f * d * d : ad - 0.5f;
}

__device__ __forceinline__ float logaddexp0(float logit) {
    return (logit > 0.0f) ? (logit + log1pf(expf(-logit))) : log1pf(expf(logit));
}

// Bitmap clear with non-temporal stores.
__global__ void clear_bitmap(uvec4* __restrict__ bmv, int bmW4) {
    const uvec4 z = (uvec4)(0u);
    const int stride = gridDim.x * blockDim.x;
    for (int k = blockIdx.x * blockDim.x + threadIdx.x; k < bmW4; k += stride)
        __builtin_nontemporal_store(z, &bmv[k]);
}

// ---------------- Plan D: bitmap membership + small row table ----------------

// Fused: set membership bits, emit compact cell id per lidar point, and
// 0xFF-fill the small row table (independent buffer; hides under atomics).
__global__ void build_bitmap(const int4* __restrict__ li, int Nl,
                             unsigned* __restrict__ bm,
                             unsigned* __restrict__ cells,
                             uvec4* __restrict__ stv, int stW4) {
    const int gid = blockIdx.x * blockDim.x + threadIdx.x;
    if (gid < Nl) {
        int4 v = li[gid];  // [b,z,y,x]
        unsigned cell = ((unsigned)(v.x * ZD + v.y) * YD + v.z) * XD + v.w;
        cells[gid] = cell;
        atomicOr(&bm[cell >> 5], 1u << (cell & 31));
    }
    const uvec4 f = (uvec4)(~0u);
    const int stride = gridDim.x * blockDim.x;
    for (int k = gid; k < stW4; k += stride)
        __builtin_nontemporal_store(f, &stv[k]);
}

// Per radar point: membership via bitmap windows, argmin tie-break via masks,
// occ/cnt/off partial sums, matched cell -> mcell[i] + CAS-insert into small table.
__global__ void __launch_bounds__(BLOCK)
main_match(const float4* __restrict__ pf, const float* __restrict__ occ,
           const int4* __restrict__ ri, const unsigned* __restrict__ bm,
           unsigned long long* __restrict__ stab, unsigned smask,
           const int* __restrict__ Rptr, int Nr,
           int* __restrict__ mcell, double* __restrict__ partials) {
    const int R = *Rptr;
    const int i = blockIdx.x * BLOCK + threadIdx.x;
    double occ_s = 0.0, cnt_s = 0.0, off_s = 0.0;

    if (i < Nr) {
        int4 rib = ri[i];
        const int b = rib.x, z = rib.y, y = rib.z, x = rib.w;
        int mc = -1;
        float m = 0.0f;
        int sx = 0, sy = 0, sz = 0;
        bool matched = false;

        if (R == 1) {
            // Gather all 27 membership bits with 9 independent u64 window loads.
            const int xa = max(x - 1, 0);
            const int xc = min(x + 1, XD - 1);
            const int sa = x - xa;        // shift for dx=0
            const int sc = xc - xa;       // shift for dx=+1
            unsigned hm = 0;
#pragma unroll
            for (int dz = -1; dz <= 1; ++dz) {
                const int zz = min(max(z + dz, 0), ZD - 1);
#pragma unroll
                for (int dy = -1; dy <= 1; ++dy) {
                    const int yy = min(max(y + dy, 0), YD - 1);
                    const unsigned n0 =
                        ((unsigned)(b * ZD + zz) * YD + yy) * XD + (unsigned)xa;
                    const unsigned q = n0 >> 5;
                    const int r = n0 & 31;
                    unsigned long long w =
                        ((unsigned long long)bm[q + 1] << 32) | bm[q];
                    w >>= r;
                    const int k0 = (dz + 1) * 9 + (dy + 1) * 3;
                    hm |= ((unsigned)(w & 1)) << (k0 + 0);
                    hm |= ((unsigned)((w >> sa) & 1)) << (k0 + 1);
                    hm |= ((unsigned)((w >> sc) & 1)) << (k0 + 2);
                }
            }
            // argmin(dL1) with first-k tie-break: distance-class masks.
            const unsigned M0 = 1u << 13;
            const unsigned M1 = (1u << 4) | (1u << 10) | (1u << 12) |
                                (1u << 14) | (1u << 16) | (1u << 22);
            const unsigned M2 = (1u << 1) | (1u << 3) | (1u << 5) | (1u << 7) |
                                (1u << 9) | (1u << 11) | (1u << 15) | (1u << 17) |
                                (1u << 19) | (1u << 21) | (1u << 23) | (1u << 25);
            int bk = -1;
            if (hm & M0)       bk = 13;
            else if (hm & M1)  bk = __ffs((int)(hm & M1)) - 1;
            else if (hm & M2)  bk = __ffs((int)(hm & M2)) - 1;
            else if (hm)       bk = __ffs((int)hm) - 1;   // distance-3 remainder
            if (bk >= 0) {
                matched = true;
                const int dz = bk / 9 - 1, dy = (bk / 3) % 3 - 1, dx = bk % 3 - 1;
                sz = min(max(z + dz, 0), ZD - 1);
                sy = min(max(y + dy, 0), YD - 1);
                sx = min(max(x + dx, 0), XD - 1);
            }
        } else {
            // Generic R: ordered triple loop (k ascending) with strict '<' update.
            int bestd = INT_MAX;
            for (int dz = -R; dz <= R; ++dz) {
                const int zz = min(max(z + dz, 0), ZD - 1);
                const int adz = abs(dz);
                for (int dy = -R; dy <= R; ++dy) {
                    const int yy = min(max(y + dy, 0), YD - 1);
                    const int adzy = adz + abs(dy);
                    for (int dx = -R; dx <= R; ++dx) {
                        const int d = adzy + abs(dx);
                        if (d >= bestd) continue;
                        const int xx = min(max(x + dx, 0), XD - 1);
                        const unsigned cell =
                            ((unsigned)(b * ZD + zz) * YD + yy) * XD + xx;
                        if ((bm[cell >> 5] >> (cell & 31)) & 1u) {
                            bestd = d; matched = true;
                            sz = zz; sy = yy; sx = xx;
                        }
                    }
                }
            }
        }

        if (matched) {
            m = 1.0f;
            cnt_s = 1.0;
            const unsigned cell = ((unsigned)(b * ZD + sz) * YD + sy) * XD + sx;
            mc = (int)cell;
            const float4 p = pf[i];
            off_s = (double)(smooth_l1(p.x - (float)(sx - x)) +
                             smooth_l1(p.y - (float)(sy - y)) +
                             smooth_l1(p.z - (float)(sz - z)));
            // Insert selected cell into small table (row filled by lidar_scan).
            const unsigned long long desired =
                ((unsigned long long)cell << 32) | 0xFFFFFFFFull;
            unsigned s = hash_mix(cell) & smask;
            while (true) {
                unsigned long long old = atomicCAS(&stab[s], EMPTY64, desired);
                if (old == EMPTY64 || (unsigned)(old >> 32) == cell) break;
                s = (s + 1) & smask;
            }
        }
        mcell[i] = mc;
        const float logit = occ[i];
        occ_s = (double)(logaddexp0(logit) - logit * m);
    }

    __shared__ double sh[3][BLOCK];
    const int tid = threadIdx.x;
    sh[0][tid] = occ_s; sh[1][tid] = cnt_s; sh[2][tid] = off_s;
    __syncthreads();
    for (int s = BLOCK / 2; s > 0; s >>= 1) {
        if (tid < s) {
            sh[0][tid] += sh[0][tid + s];
            sh[1][tid] += sh[1][tid + s];
            sh[2][tid] += sh[2][tid + s];
        }
        __syncthreads();
    }
    if (tid == 0) {
        partials[blockIdx.x * 4 + 0] = sh[0][0];
        partials[blockIdx.x * 4 + 1] = sh[1][0];
        partials[blockIdx.x * 4 + 2] = sh[2][0];
        partials[blockIdx.x * 4 + 3] = 0.0;   // feat comes from feat_pass
    }
}

// For every lidar point: if its cell was selected by some radar point,
// atomicMin the lidar row (min row == stable argsort + leftmost searchsorted).
__global__ void lidar_scan(const unsigned* __restrict__ cells, int Nl,
                           unsigned long long* __restrict__ stab, unsigned smask) {
    int j = blockIdx.x * blockDim.x + threadIdx.x;
    if (j >= Nl) return;
    const unsigned cell = cells[j];
    unsigned s = hash_mix(cell) & smask;
    while (true) {
        const unsigned long long e = stab[s];
        if (e == EMPTY64) return;                       // cell not selected
        if ((unsigned)(e >> 32) == cell) {
            atomicMin((unsigned*)&stab[s], (unsigned)j); // low 32 bits = row
            return;
        }
        s = (s + 1) & smask;
    }
}

__global__ void __launch_bounds__(BLOCK)
feat_pass(const float4* __restrict__ pf, const int* __restrict__ mcell,
          const unsigned long long* __restrict__ stab, unsigned smask,
          const float4* __restrict__ lf, int Nr, double* __restrict__ fpart) {
    const int i = blockIdx.x * BLOCK + threadIdx.x;
    double fs = 0.0;
    if (i < Nr) {
        const int mc = mcell[i];
        if (mc >= 0) {
            const unsigned cell = (unsigned)mc;
            unsigned s = hash_mix(cell) & smask;
            unsigned row = 0;
            while (true) {
                const unsigned long long e = stab[s];
                if ((unsigned)(e >> 32) == cell) { row = (unsigned)e; break; }
                s = (s + 1) & smask;
            }
            fs = (double)fabsf(pf[i].w - lf[row].w);
        }
    }
    __shared__ double sh[BLOCK];
    const int tid = threadIdx.x;
    sh[tid] = fs;
    __syncthreads();
    for (int s = BLOCK / 2; s > 0; s >>= 1) {
        if (tid < s) sh[tid] += sh[tid + s];
        __syncthreads();
    }
    if (tid == 0) fpart[blockIdx.x] = sh[0];
}

// ---------------- Fallback: merged u64 hash table (ws too small) ----------------

__global__ void fb_insert(const int4* __restrict__ li, int Nl,
                          unsigned long long* __restrict__ tab, unsigned cmask) {
    int i = blockIdx.x * blockDim.x + threadIdx.x;
    if (i >= Nl) return;
    int4 v = li[i];
    const unsigned cell = ((unsigned)(v.x * ZD + v.y) * YD + v.z) * XD + v.w;
    const unsigned long long desired = ((unsigned long long)cell << 32) | (unsigned)i;
    unsigned s = hash_mix(cell) & cmask;
    unsigned probes = 0;
    while (probes++ <= cmask) {
        const unsigned long long old = atomicCAS(&tab[s], EMPTY64, desired);
        if (old == EMPTY64) return;
        if ((unsigned)(old >> 32) == cell) {
            atomicMin((unsigned*)&tab[s], (unsigned)i);
            return;
        }
        s = (s + 1) & cmask;
    }
}

__global__ void __launch_bounds__(BLOCK)
fb_main(const float4* __restrict__ pf, const float* __restrict__ occ,
        const int4* __restrict__ ri, const float4* __restrict__ lf,
        const unsigned long long* __restrict__ tab, unsigned cmask,
        const int* __restrict__ Rptr, int Nr, double* __restrict__ partials) {
    const int R = *Rptr;
    const int i = blockIdx.x * BLOCK + threadIdx.x;
    double occ_s = 0.0, cnt_s = 0.0, off_s = 0.0, feat_s = 0.0;
    if (i < Nr) {
        int4 rib = ri[i];
        const int b = rib.x, z = rib.y, y = rib.z, x = rib.w;
        int bestd = INT_MAX, bestRow = -1;
        int sx = 0, sy = 0, sz = 0;
        for (int dz = -R; dz <= R; ++dz) {
            const int zz = min(max(z + dz, 0), ZD - 1);
            const int adz = abs(dz);
            for (int dy = -R; dy <= R; ++dy) {
                const int yy = min(max(y + dy, 0), YD - 1);
                const int adzy = adz + abs(dy);
                for (int dx = -R; dx <= R; ++dx) {
                    const int d = adzy + abs(dx);
                    if (d >= bestd) continue;
                    const int xx = min(max(x + dx, 0), XD - 1);
                    const unsigned cell =
                        ((unsigned)(b * ZD + zz) * YD + yy) * XD + xx;
                    unsigned s = hash_mix(cell) & cmask;
                    int row = -1;
                    while (true) {
                        const unsigned long long e = tab[s];
                        if ((unsigned)(e >> 32) == cell) { row = (int)(unsigned)e; break; }
                        if (e == EMPTY64) break;
                        s = (s + 1) & cmask;
                    }
                    if (row >= 0) { bestd = d; bestRow = row; sz = zz; sy = yy; sx = xx; }
                }
            }
        }
        const float m = (bestRow >= 0) ? 1.0f : 0.0f;
        const float logit = occ[i];
        occ_s = (double)(logaddexp0(logit) - logit * m);
        if (bestRow >= 0) {
            cnt_s = 1.0;
            const float4 p = pf[i];
            off_s = (double)(smooth_l1(p.x - (float)(sx - x)) +
                             smooth_l1(p.y - (float)(sy - y)) +
                             smooth_l1(p.z - (float)(sz - z)));
            feat_s = (double)fabsf(p.w - lf[bestRow].w);
        }
    }
    __shared__ double sh[4][BLOCK];
    const int tid = threadIdx.x;
    sh[0][tid] = occ_s; sh[1][tid] = cnt_s; sh[2][tid] = off_s; sh[3][tid] = feat_s;
    __syncthreads();
    for (int s = BLOCK / 2; s > 0; s >>= 1) {
        if (tid < s) {
            sh[0][tid] += sh[0][tid + s];
            sh[1][tid] += sh[1][tid + s];
            sh[2][tid] += sh[2][tid + s];
            sh[3][tid] += sh[3][tid + s];
        }
        __syncthreads();
    }
    if (tid == 0) {
        partials[blockIdx.x * 4 + 0] = sh[0][0];
        partials[blockIdx.x * 4 + 1] = sh[1][0];
        partials[blockIdx.x * 4 + 2] = sh[2][0];
        partials[blockIdx.x * 4 + 3] = sh[3][0];
    }
}

// ---------------- Finalize ----------------

__global__ void finalize_kernel(const double* __restrict__ partials,
                                const double* __restrict__ fpart, int nblk,
                                int Nr, float* __restrict__ out) {
    __shared__ double sh[4][BLOCK];
    const int tid = threadIdx.x;
    double a0 = 0, a1 = 0, a2 = 0, a3 = 0;
    for (int i = tid; i < nblk; i += BLOCK) {
        a0 += partials[i * 4 + 0];
        a1 += partials[i * 4 + 1];
        a2 += partials[i * 4 + 2];
        a3 += partials[i * 4 + 3] + fpart[i];
    }
    sh[0][tid] = a0; sh[1][tid] = a1; sh[2][tid] = a2; sh[3][tid] = a3;
    __syncthreads();
    for (int s = BLOCK / 2; s > 0; s >>= 1) {
        if (tid < s) {
            sh[0][tid] += sh[0][tid + s];
            sh[1][tid] += sh[1][tid + s];
            sh[2][tid] += sh[2][tid + s];
            sh[3][tid] += sh[3][tid + s];
        }
        __syncthreads();
    }
    if (tid == 0) {
        const double occ_loss = sh[0][0] / (double)Nr;
        const double cnt = sh[1][0];
        const double off_loss = sh[2][0] / fmax(cnt * 3.0, 1.0);
        const double feat_loss = sh[3][0] / fmax(cnt, 1.0);
        out[0] = (float)(0.2 * occ_loss + 1.0 * off_loss + 1.0 * feat_loss);
    }
}

extern "C" void kernel_launch(void* const* d_in, const int* in_sizes, int n_in,
                              void* d_out, int out_size, void* d_ws, size_t ws_size,
                              hipStream_t stream) {
    const float* pred_feat  = (const float*)d_in[0];   // (Nr,4)
    const float* pred_occ   = (const float*)d_in[1];   // (Nr,1,1)
    const int*   radar_idx  = (const int*)d_in[2];     // (Nr,4)
    const float* lidar_feat = (const float*)d_in[3];   // (Nl,4)
    const int*   lidar_idx  = (const int*)d_in[4];     // (Nl,4)
    const int*   Rptr       = (const int*)d_in[5];     // scalar (device)

    const int Nr = in_sizes[0] / 4;
    const int Nl = in_sizes[3] / 4;
    const int nblk  = (Nr + BLOCK - 1) / BLOCK;
    const int nblkL = (Nl + BLOCK - 1) / BLOCK;

    // Plan-D workspace layout
    size_t off = 0;
    auto alloc = [&](size_t n) { size_t o = off; off += (n + 255) & ~(size_t)255; return o; };
    const size_t bmBytes   = (size_t)BZYX / 8 + 64;          // bitmap + window pad
    const size_t stabBytes = (size_t)8 << SMALL_LOG;         // 4 MB
    const size_t bmOff   = alloc(bmBytes);
    const size_t stabOff = alloc(stabBytes);
    const size_t cellOff = alloc((size_t)Nl * 4);
    const size_t mcOff   = alloc((size_t)Nr * 4);
    const size_t pOff    = alloc((size_t)nblk * 4 * sizeof(double));
    const size_t fpOff   = alloc((size_t)nblk * sizeof(double));
    const size_t needD = off;

    char* ws = (char*)d_ws;
    if (needD <= ws_size) {
        unsigned*           bm    = (unsigned*)(ws + bmOff);
        unsigned long long* stab  = (unsigned long long*)(ws + stabOff);
        unsigned*           cells = (unsigned*)(ws + cellOff);
        int*                mcell = (int*)(ws + mcOff);
        double*             parts = (double*)(ws + pOff);
        double*             fpart = (double*)(ws + fpOff);
        const unsigned smask = (1u << SMALL_LOG) - 1;
        const int stW4 = (int)(stabBytes / 16);

        clear_bitmap<<<4096, BLOCK, 0, stream>>>((uvec4*)bm, (int)(bmBytes / 16));
        build_bitmap<<<nblkL, BLOCK, 0, stream>>>(
            (const int4*)lidar_idx, Nl, bm, cells, (uvec4*)stab, stW4);
        main_match<<<nblk, BLOCK, 0, stream>>>(
            (const float4*)pred_feat, pred_occ, (const int4*)radar_idx,
            bm, stab, smask, Rptr, Nr, mcell, parts);
        lidar_scan<<<nblkL, BLOCK, 0, stream>>>(cells, Nl, stab, smask);
        feat_pass<<<nblk, BLOCK, 0, stream>>>(
            (const float4*)pred_feat, mcell, stab, smask,
            (const float4*)lidar_feat, Nr, fpart);
        finalize_kernel<<<1, BLOCK, 0, stream>>>(parts, fpart, nblk, Nr, (float*)d_out);
    } else {
        // Fallback: merged u64 open-addressing table
        const size_t tailBytes = (size_t)nblk * 5 * sizeof(double) + 512;
        unsigned C = 1u << 22;
        while ((size_t)C * 8 + tailBytes > ws_size && C > (1u << 21)) C >>= 1;
        const unsigned cmask = C - 1;
        unsigned long long* tab = (unsigned long long*)ws;
        double* parts = (double*)(ws + ((size_t)C * 8 + 255 & ~(size_t)255));
        double* fpart = parts + (size_t)nblk * 4;

        hipError_t e1 = hipMemsetAsync(tab, 0xFF, (size_t)C * 8, stream); (void)e1;
        hipError_t e2 = hipMemsetAsync(fpart, 0x00, (size_t)nblk * sizeof(double), stream); (void)e2;

        fb_insert<<<nblkL, BLOCK, 0, stream>>>((const int4*)lidar_idx, Nl, tab, cmask);
        fb_main<<<nblk, BLOCK, 0, stream>>>(
            (const float4*)pred_feat, pred_occ, (const int4*)radar_idx,
            (const float4*)lidar_feat, tab, cmask, Rptr, Nr, parts);
        finalize_kernel<<<1, BLOCK, 0, stream>>>(parts, fpart, nblk, Nr, (float*)d_out);
    }
}